// Round 4
// baseline (212.257 us; speedup 1.0000x reference)
//
#include <hip/hip_runtime.h>
#include <math.h>

#define S_LEN 56
#define DH 128

typedef float f32x4 __attribute__((ext_vector_type(4)));
typedef unsigned short u16x8 __attribute__((ext_vector_type(8)));
typedef unsigned short u16x4 __attribute__((ext_vector_type(4)));

__device__ __forceinline__ unsigned short f2bf(float f) {
  unsigned int u = __builtin_bit_cast(unsigned int, f);
  u += 0x7fffu + ((u >> 16) & 1u);  // RNE
  return (unsigned short)(u >> 16);
}
__device__ __forceinline__ unsigned short tobf(float f) {
  __bf16 h = (__bf16)f;
  return __builtin_bit_cast(unsigned short, h);
}
__device__ __forceinline__ u16x4 pk4(f32x4 v) {
  u16x4 r;
  r[0] = tobf(v[0]); r[1] = tobf(v[1]); r[2] = tobf(v[2]); r[3] = tobf(v[3]);
  return r;
}
__device__ __forceinline__ u16x8 pk8(f32x4 a, f32x4 b) {
  u16x8 r;
  r[0] = tobf(a[0]); r[1] = tobf(a[1]); r[2] = tobf(a[2]); r[3] = tobf(a[3]);
  r[4] = tobf(b[0]); r[5] = tobf(b[1]); r[6] = tobf(b[2]); r[7] = tobf(b[3]);
  return r;
}

template <typename V>
__device__ __forceinline__ auto mfma_sel(V a, V b, f32x4 c, int)
    -> decltype(__builtin_amdgcn_mfma_f32_16x16x32_bf16(a, b, c, 0, 0, 0)) {
  return __builtin_amdgcn_mfma_f32_16x16x32_bf16(a, b, c, 0, 0, 0);
}
template <typename V, typename E = __bf16>
__device__ __forceinline__ f32x4 mfma_sel(V a, V b, f32x4 c, long) {
  typedef E bfv __attribute__((ext_vector_type(8)));
  return __builtin_amdgcn_mfma_f32_16x16x32_bf16(
      __builtin_bit_cast(bfv, a), __builtin_bit_cast(bfv, b), c, 0, 0, 0);
}
__device__ __forceinline__ f32x4 MFMA(u16x8 a, u16x8 b, f32x4 c) {
  return mfma_sel(a, b, c, 0);
}

// XOR swizzle for row-major LDS tiles (row stride 2^LRB bytes).
template <int LRB>
__device__ __forceinline__ int swz(int row, int col) {
  int byteoff = (row << LRB) + (col << 1);
  byteoff ^= (row & 7) << 4;
  return byteoff >> 1;  // ushort index
}

__global__ void conv_w(const float* __restrict__ wq, const float* __restrict__ wk,
                       const float* __restrict__ wv, const float* __restrict__ wo,
                       unsigned short* __restrict__ o) {
  int i = blockIdx.x * 256 + threadIdx.x;  // 0..65535
  int m = i >> 14, r = i & 16383;
  const float* src = (m == 0) ? wq : (m == 1) ? wk : (m == 2) ? wv : wo;
  o[i] = f2bf(src[r]);
}

// Hybrid: r3's all-register E^T path (Q^T/K^T swapped-operand MFMA, in-reg
// softmax) + round-1-PROVEN PV/out path (P'->LDS, vt[d][s], GEMM3/4 as r1).
__global__ __launch_bounds__(256, 2) void tb_fused(
    const float* __restrict__ xg, const unsigned short* __restrict__ wbf,
    const int* __restrict__ lens, float* __restrict__ outg,
    float* __restrict__ attng) {
  __shared__ __align__(16) unsigned short xs[64 * DH];   // x bf16 -> later O
  __shared__ __align__(16) unsigned short vt[DH * 64];   // V^T [d][s], r1 layout
  __shared__ __align__(16) unsigned short ps[64 * 64];   // P' [q][k']

  const int b = blockIdx.x;
  const int tid = threadIdx.x;
  const int lane = tid & 63;
  const int w = tid >> 6;     // wave 0..3, owns q-rows [16w, 16w+16)
  const int l15 = lane & 15;
  const int lq = lane >> 4;   // 0..3
  const int n0w = w << 5;

  const int len = lens[b];
  const float* __restrict__ xb = xg + (size_t)b * (S_LEN * DH);

  // ---- x -> LDS bf16 (swizzled), rows 56..63 zeroed ----
#pragma unroll
  for (int i = 0; i < 8; ++i) {
    int e4 = tid + (i << 8);
    int row = e4 >> 5;
    int col = (e4 & 31) << 2;
    u16x4 h = {0, 0, 0, 0};
    if (row < S_LEN) {
      f32x4 v = *(const f32x4*)(xb + (e4 << 2));
      h = pk4(v);
    }
    *(u16x4*)&xs[swz<8>(row, col)] = h;
  }
  __syncthreads();  // B1: x visible

  // x fragments cached: af[mt][kt] (lane=row l15, 8 k-elems at 32kt+8lq+j)
  u16x8 af[4][4];
#pragma unroll
  for (int mt = 0; mt < 4; ++mt)
#pragma unroll
    for (int kt = 0; kt < 4; ++kt)
      af[mt][kt] = *(const u16x8*)&xs[swz<8>((mt << 4) + l15, (kt << 5) + (lq << 3))];
  // wave's own q-tile fragments (static copies; af[w] would be runtime-indexed)
  u16x8 aq[4];
#pragma unroll
  for (int kt = 0; kt < 4; ++kt)
    aq[kt] = *(const u16x8*)&xs[swz<8>((w << 4) + l15, (kt << 5) + (lq << 3))];

  // ---- V = x @ Wv^T (n-split across waves), r1-style store vt[d][s] ----
  {
    const unsigned short* __restrict__ wv = wbf + 2 * (DH * DH);
    u16x8 bfr[4][2];
#pragma unroll
    for (int kt = 0; kt < 4; ++kt)
#pragma unroll
      for (int nt = 0; nt < 2; ++nt)
        bfr[kt][nt] = *(const u16x8*)&wv[(n0w + (nt << 4) + l15) * DH + (kt << 5) + (lq << 3)];
    f32x4 vacc[4][2];
#pragma unroll
    for (int mt = 0; mt < 4; ++mt)
#pragma unroll
      for (int nt = 0; nt < 2; ++nt) vacc[mt][nt] = f32x4{0.f, 0.f, 0.f, 0.f};
#pragma unroll
    for (int kt = 0; kt < 4; ++kt)
#pragma unroll
      for (int mt = 0; mt < 4; ++mt)
#pragma unroll
        for (int nt = 0; nt < 2; ++nt)
          vacc[mt][nt] = MFMA(af[mt][kt], bfr[kt][nt], vacc[mt][nt]);
#pragma unroll
    for (int mt = 0; mt < 4; ++mt)
#pragma unroll
      for (int nt = 0; nt < 2; ++nt) {
        int d = n0w + (nt << 4) + l15;
        int rowb = (mt << 4) + (lq << 2);  // s base
        *(u16x4*)&vt[swz<7>(d, rowb)] = pk4(vacc[mt][nt]);
      }
  }

  // ---- E^T path (r3): Q^T,K^T as C/D, pair-packed K=32 accumulation ----
  f32x4 Ea[4];
#pragma unroll
  for (int nt = 0; nt < 4; ++nt) Ea[nt] = f32x4{0.f, 0.f, 0.f, 0.f};

  const unsigned short* __restrict__ wq = wbf;
  const unsigned short* __restrict__ wk = wbf + DH * DH;
#pragma unroll
  for (int tp = 0; tp < 4; ++tp) {
    const int t0 = tp * 2, t1 = t0 + 1;
    u16x8 qp;
    {
      u16x8 wf0[4], wf1[4];
#pragma unroll
      for (int kt = 0; kt < 4; ++kt) {
        wf0[kt] = *(const u16x8*)&wq[((t0 << 4) + l15) * DH + (kt << 5) + (lq << 3)];
        wf1[kt] = *(const u16x8*)&wq[((t1 << 4) + l15) * DH + (kt << 5) + (lq << 3)];
      }
      f32x4 qa0 = {0.f, 0.f, 0.f, 0.f}, qa1 = {0.f, 0.f, 0.f, 0.f};
#pragma unroll
      for (int kt = 0; kt < 4; ++kt) {
        qa0 = MFMA(wf0[kt], aq[kt], qa0);
        qa1 = MFMA(wf1[kt], aq[kt], qa1);
      }
      qp = pk8(qa0, qa1);
    }
    {
      u16x8 wf0[4], wf1[4];
#pragma unroll
      for (int kt = 0; kt < 4; ++kt) {
        wf0[kt] = *(const u16x8*)&wk[((t0 << 4) + l15) * DH + (kt << 5) + (lq << 3)];
        wf1[kt] = *(const u16x8*)&wk[((t1 << 4) + l15) * DH + (kt << 5) + (lq << 3)];
      }
      f32x4 ka[4][2];
#pragma unroll
      for (int nt = 0; nt < 4; ++nt) {
        ka[nt][0] = f32x4{0.f, 0.f, 0.f, 0.f};
        ka[nt][1] = f32x4{0.f, 0.f, 0.f, 0.f};
      }
#pragma unroll
      for (int kt = 0; kt < 4; ++kt)
#pragma unroll
        for (int nt = 0; nt < 4; ++nt) {
          ka[nt][0] = MFMA(wf0[kt], af[nt][kt], ka[nt][0]);
          ka[nt][1] = MFMA(wf1[kt], af[nt][kt], ka[nt][1]);
        }
#pragma unroll
      for (int nt = 0; nt < 4; ++nt) {
        u16x8 kp = pk8(ka[nt][0], ka[nt][1]);
        Ea[nt] = MFMA(kp, qp, Ea[nt]);
      }
    }
  }

  // ---- scale, mask, softmax (per-lane: q = 16w+l15, k' = 16nt+4lq+r) ----
  const float sca = 0.08838834764831845f;  // 1/sqrt(128)
#pragma unroll
  for (int nt = 0; nt < 4; ++nt)
#pragma unroll
    for (int r = 0; r < 4; ++r) {
      int kk = (nt << 4) + (lq << 2) + r;
      Ea[nt][r] = (kk < len) ? Ea[nt][r] * sca : -1e30f;
    }
  float m = -1e30f;
#pragma unroll
  for (int nt = 0; nt < 4; ++nt)
    m = fmaxf(m, fmaxf(fmaxf(Ea[nt][0], Ea[nt][1]), fmaxf(Ea[nt][2], Ea[nt][3])));
  m = fmaxf(m, __shfl_xor(m, 16, 64));
  m = fmaxf(m, __shfl_xor(m, 32, 64));
  float s = 0.f;
#pragma unroll
  for (int nt = 0; nt < 4; ++nt)
#pragma unroll
    for (int r = 0; r < 4; ++r) {
      float p = __expf(Ea[nt][r] - m);
      Ea[nt][r] = p;
      s += p;
    }
  s += __shfl_xor(s, 16, 64);
  s += __shfl_xor(s, 32, 64);
  const float inv = 1.f / s;

  // ---- attn store (f32x4) + P' -> ps[q][k'] (r1-consumable layout) ----
  const int q = (w << 4) + l15;
  float* __restrict__ ab = attng + (size_t)b * (S_LEN * S_LEN);
  const float islen = inv * sqrtf((float)len);
#pragma unroll
  for (int nt = 0; nt < 4; ++nt) {
    int cs = (nt << 4) + (lq << 2);
    f32x4 pv = Ea[nt] * inv;
    if (q < S_LEN && cs < S_LEN) *(f32x4*)&ab[q * S_LEN + cs] = pv;
#pragma unroll
    for (int r = 0; r < 4; ++r) ps[swz<7>(q, cs + r)] = tobf(Ea[nt][r] * islen);
  }
  __syncthreads();  // B2: vt + ps visible

  // ---- GEMM3 (r1-proven): O = P' V ; O -> xs ----
  u16x8 ap[2];
#pragma unroll
  for (int kt = 0; kt < 2; ++kt)
    ap[kt] = *(const u16x8*)&ps[swz<7>((w << 4) + l15, (kt << 5) + (lq << 3))];
#pragma unroll
  for (int nt = 0; nt < 8; ++nt) {
    f32x4 a = f32x4{0.f, 0.f, 0.f, 0.f};
#pragma unroll
    for (int kt = 0; kt < 2; ++kt) {
      u16x8 bv = *(const u16x8*)&vt[swz<7>((nt << 4) + l15, (kt << 5) + (lq << 3))];
      a = MFMA(ap[kt], bv, a);
    }
    int dcol = (nt << 4) + l15;
    int rowb = (w << 4) + (lq << 2);
#pragma unroll
    for (int r = 0; r < 4; ++r) xs[swz<8>(rowb + r, dcol)] = f2bf(a[r]);
  }
  __syncthreads();  // B3: O visible

  // ---- GEMM4 (r1-proven): out = O @ Wo^T ----
  const unsigned short* __restrict__ wo = wbf + 3 * (DH * DH);
  u16x8 ao[4][4];
#pragma unroll
  for (int mt = 0; mt < 4; ++mt)
#pragma unroll
    for (int kt = 0; kt < 4; ++kt)
      ao[mt][kt] = *(const u16x8*)&xs[swz<8>((mt << 4) + l15, (kt << 5) + (lq << 3))];
  float* __restrict__ ob = outg + (size_t)b * (S_LEN * DH);
#pragma unroll
  for (int nt = 0; nt < 2; ++nt) {
    int dcol = n0w + (nt << 4) + l15;
    f32x4 acc[4];
#pragma unroll
    for (int mt = 0; mt < 4; ++mt) acc[mt] = f32x4{0.f, 0.f, 0.f, 0.f};
#pragma unroll
    for (int kt = 0; kt < 4; ++kt) {
      u16x8 bo = *(const u16x8*)&wo[dcol * DH + (kt << 5) + (lq << 3)];
#pragma unroll
      for (int mt = 0; mt < 4; ++mt) acc[mt] = MFMA(ao[mt][kt], bo, acc[mt]);
    }
#pragma unroll
    for (int mt = 0; mt < 4; ++mt) {
      int rowb = (mt << 4) + (lq << 2);
#pragma unroll
      for (int r = 0; r < 4; ++r) {
        int sr = rowb + r;
        if (sr < S_LEN) ob[sr * DH + dcol] = acc[mt][r];
      }
    }
  }
}

extern "C" void kernel_launch(void* const* d_in, const int* in_sizes, int n_in,
                              void* d_out, int out_size, void* d_ws, size_t ws_size,
                              hipStream_t stream) {
  const float* x  = (const float*)d_in[0];
  const float* wq = (const float*)d_in[1];
  const float* wk = (const float*)d_in[2];
  const float* wv = (const float*)d_in[3];
  const float* wo = (const float*)d_in[4];
  // d_in[5] = mask (redundant with len_sequence; unused)
  const int* lens = (const int*)d_in[6];
  const int B = in_sizes[6];  // 4096

  float* out = (float*)d_out;
  float* attn = out + (size_t)B * S_LEN * DH;
  unsigned short* wbf = (unsigned short*)d_ws;  // 4 x 128 x 128 bf16 = 128 KB

  conv_w<<<256, 256, 0, stream>>>(wq, wk, wv, wo, wbf);
  tb_fused<<<B, 256, 0, stream>>>(x, wbf, lens, out, attn);
}

// Round 5
// 211.866 us; speedup vs baseline: 1.0018x; 1.0018x over previous
//
#include <hip/hip_runtime.h>
#include <math.h>

#define S_LEN 56
#define DH 128

typedef float f32x4 __attribute__((ext_vector_type(4)));
typedef unsigned short u16x8 __attribute__((ext_vector_type(8)));
typedef unsigned short u16x4 __attribute__((ext_vector_type(4)));

__device__ __forceinline__ unsigned short f2bf(float f) {
  unsigned int u = __builtin_bit_cast(unsigned int, f);
  u += 0x7fffu + ((u >> 16) & 1u);  // RNE
  return (unsigned short)(u >> 16);
}
__device__ __forceinline__ unsigned short tobf(float f) {
  __bf16 h = (__bf16)f;
  return __builtin_bit_cast(unsigned short, h);
}
__device__ __forceinline__ u16x4 pk4(f32x4 v) {
  u16x4 r;
  r[0] = tobf(v[0]); r[1] = tobf(v[1]); r[2] = tobf(v[2]); r[3] = tobf(v[3]);
  return r;
}
__device__ __forceinline__ u16x8 pk8(f32x4 a, f32x4 b) {
  u16x8 r;
  r[0] = tobf(a[0]); r[1] = tobf(a[1]); r[2] = tobf(a[2]); r[3] = tobf(a[3]);
  r[4] = tobf(b[0]); r[5] = tobf(b[1]); r[6] = tobf(b[2]); r[7] = tobf(b[3]);
  return r;
}

template <typename V>
__device__ __forceinline__ auto mfma_sel(V a, V b, f32x4 c, int)
    -> decltype(__builtin_amdgcn_mfma_f32_16x16x32_bf16(a, b, c, 0, 0, 0)) {
  return __builtin_amdgcn_mfma_f32_16x16x32_bf16(a, b, c, 0, 0, 0);
}
template <typename V, typename E = __bf16>
__device__ __forceinline__ f32x4 mfma_sel(V a, V b, f32x4 c, long) {
  typedef E bfv __attribute__((ext_vector_type(8)));
  return __builtin_amdgcn_mfma_f32_16x16x32_bf16(
      __builtin_bit_cast(bfv, a), __builtin_bit_cast(bfv, b), c, 0, 0, 0);
}
__device__ __forceinline__ f32x4 MFMA(u16x8 a, u16x8 b, f32x4 c) {
  return mfma_sel(a, b, c, 0);
}

// XOR swizzle for row-major LDS tiles (row stride 2^LRB bytes).
template <int LRB>
__device__ __forceinline__ int swz(int row, int col) {
  int byteoff = (row << LRB) + (col << 1);
  byteoff ^= (row & 7) << 4;
  return byteoff >> 1;  // ushort index
}

__global__ void conv_w(const float* __restrict__ wq, const float* __restrict__ wk,
                       const float* __restrict__ wv, const float* __restrict__ wo,
                       unsigned short* __restrict__ o) {
  int i = blockIdx.x * 256 + threadIdx.x;  // 0..65535
  int m = i >> 14, r = i & 16383;
  const float* src = (m == 0) ? wq : (m == 1) ? wk : (m == 2) ? wv : wo;
  o[i] = f2bf(src[r]);
}

// Hybrid: r3's all-register E^T path (Q^T/K^T swapped-operand MFMA, in-reg
// softmax) + round-1-PROVEN PV/out path (P'->LDS, vt[d][s], GEMM3/4 as r1).
__global__ __launch_bounds__(256, 2) void tb_fused(
    const float* __restrict__ xg, const unsigned short* __restrict__ wbf,
    const int* __restrict__ lens, float* __restrict__ outg,
    float* __restrict__ attng) {
  __shared__ __align__(16) unsigned short xs[64 * DH];   // x bf16 -> later O
  __shared__ __align__(16) unsigned short vt[DH * 64];   // V^T [d][s], r1 layout
  __shared__ __align__(16) unsigned short ps[64 * 64];   // P' [q][k']

  const int b = blockIdx.x;
  const int tid = threadIdx.x;
  const int lane = tid & 63;
  const int w = tid >> 6;     // wave 0..3, owns q-rows [16w, 16w+16)
  const int l15 = lane & 15;
  const int lq = lane >> 4;   // 0..3
  const int n0w = w << 5;

  const int len = lens[b];
  const float* __restrict__ xb = xg + (size_t)b * (S_LEN * DH);

  // ---- x -> LDS bf16 (swizzled), rows 56..63 zeroed ----
#pragma unroll
  for (int i = 0; i < 8; ++i) {
    int e4 = tid + (i << 8);
    int row = e4 >> 5;
    int col = (e4 & 31) << 2;
    u16x4 h = {0, 0, 0, 0};
    if (row < S_LEN) {
      f32x4 v = *(const f32x4*)(xb + (e4 << 2));
      h = pk4(v);
    }
    *(u16x4*)&xs[swz<8>(row, col)] = h;
  }
  __syncthreads();  // B1: x visible

  // x fragments cached: af[mt][kt] (lane=row l15, 8 k-elems at 32kt+8lq+j)
  u16x8 af[4][4];
#pragma unroll
  for (int mt = 0; mt < 4; ++mt)
#pragma unroll
    for (int kt = 0; kt < 4; ++kt)
      af[mt][kt] = *(const u16x8*)&xs[swz<8>((mt << 4) + l15, (kt << 5) + (lq << 3))];
  // wave's own q-tile fragments (static copies; af[w] would be runtime-indexed)
  u16x8 aq[4];
#pragma unroll
  for (int kt = 0; kt < 4; ++kt)
    aq[kt] = *(const u16x8*)&xs[swz<8>((w << 4) + l15, (kt << 5) + (lq << 3))];

  // ---- V = x @ Wv^T (n-split across waves), r1-style store vt[d][s] ----
  {
    const unsigned short* __restrict__ wv = wbf + 2 * (DH * DH);
    u16x8 bfr[4][2];
#pragma unroll
    for (int kt = 0; kt < 4; ++kt)
#pragma unroll
      for (int nt = 0; nt < 2; ++nt)
        bfr[kt][nt] = *(const u16x8*)&wv[(n0w + (nt << 4) + l15) * DH + (kt << 5) + (lq << 3)];
    f32x4 vacc[4][2];
#pragma unroll
    for (int mt = 0; mt < 4; ++mt)
#pragma unroll
      for (int nt = 0; nt < 2; ++nt) vacc[mt][nt] = f32x4{0.f, 0.f, 0.f, 0.f};
#pragma unroll
    for (int kt = 0; kt < 4; ++kt)
#pragma unroll
      for (int mt = 0; mt < 4; ++mt)
#pragma unroll
        for (int nt = 0; nt < 2; ++nt)
          vacc[mt][nt] = MFMA(af[mt][kt], bfr[kt][nt], vacc[mt][nt]);
#pragma unroll
    for (int mt = 0; mt < 4; ++mt)
#pragma unroll
      for (int nt = 0; nt < 2; ++nt) {
        int d = n0w + (nt << 4) + l15;
        int rowb = (mt << 4) + (lq << 2);  // s base
        *(u16x4*)&vt[swz<7>(d, rowb)] = pk4(vacc[mt][nt]);
      }
  }

  // ---- E^T path (r3): Q^T,K^T as C/D, pair-packed K=32 accumulation ----
  f32x4 Ea[4];
#pragma unroll
  for (int nt = 0; nt < 4; ++nt) Ea[nt] = f32x4{0.f, 0.f, 0.f, 0.f};

  const unsigned short* __restrict__ wq = wbf;
  const unsigned short* __restrict__ wk = wbf + DH * DH;
#pragma unroll
  for (int tp = 0; tp < 4; ++tp) {
    const int t0 = tp * 2, t1 = t0 + 1;
    u16x8 qp;
    {
      u16x8 wf0[4], wf1[4];
#pragma unroll
      for (int kt = 0; kt < 4; ++kt) {
        wf0[kt] = *(const u16x8*)&wq[((t0 << 4) + l15) * DH + (kt << 5) + (lq << 3)];
        wf1[kt] = *(const u16x8*)&wq[((t1 << 4) + l15) * DH + (kt << 5) + (lq << 3)];
      }
      f32x4 qa0 = {0.f, 0.f, 0.f, 0.f}, qa1 = {0.f, 0.f, 0.f, 0.f};
#pragma unroll
      for (int kt = 0; kt < 4; ++kt) {
        qa0 = MFMA(wf0[kt], aq[kt], qa0);
        qa1 = MFMA(wf1[kt], aq[kt], qa1);
      }
      qp = pk8(qa0, qa1);
    }
    {
      u16x8 wf0[4], wf1[4];
#pragma unroll
      for (int kt = 0; kt < 4; ++kt) {
        wf0[kt] = *(const u16x8*)&wk[((t0 << 4) + l15) * DH + (kt << 5) + (lq << 3)];
        wf1[kt] = *(const u16x8*)&wk[((t1 << 4) + l15) * DH + (kt << 5) + (lq << 3)];
      }
      f32x4 ka[4][2];
#pragma unroll
      for (int nt = 0; nt < 4; ++nt) {
        ka[nt][0] = f32x4{0.f, 0.f, 0.f, 0.f};
        ka[nt][1] = f32x4{0.f, 0.f, 0.f, 0.f};
      }
#pragma unroll
      for (int kt = 0; kt < 4; ++kt)
#pragma unroll
        for (int nt = 0; nt < 4; ++nt) {
          ka[nt][0] = MFMA(wf0[kt], af[nt][kt], ka[nt][0]);
          ka[nt][1] = MFMA(wf1[kt], af[nt][kt], ka[nt][1]);
        }
#pragma unroll
      for (int nt = 0; nt < 4; ++nt) {
        u16x8 kp = pk8(ka[nt][0], ka[nt][1]);
        Ea[nt] = MFMA(kp, qp, Ea[nt]);
      }
    }
  }

  // ---- scale, mask, softmax (per-lane: q = 16w+l15, k' = 16nt+4lq+r) ----
  const float sca = 0.08838834764831845f;  // 1/sqrt(128)
#pragma unroll
  for (int nt = 0; nt < 4; ++nt)
#pragma unroll
    for (int r = 0; r < 4; ++r) {
      int kk = (nt << 4) + (lq << 2) + r;
      Ea[nt][r] = (kk < len) ? Ea[nt][r] * sca : -1e30f;
    }
  float m = -1e30f;
#pragma unroll
  for (int nt = 0; nt < 4; ++nt)
    m = fmaxf(m, fmaxf(fmaxf(Ea[nt][0], Ea[nt][1]), fmaxf(Ea[nt][2], Ea[nt][3])));
  m = fmaxf(m, __shfl_xor(m, 16, 64));
  m = fmaxf(m, __shfl_xor(m, 32, 64));
  float s = 0.f;
#pragma unroll
  for (int nt = 0; nt < 4; ++nt)
#pragma unroll
    for (int r = 0; r < 4; ++r) {
      float p = __expf(Ea[nt][r] - m);
      Ea[nt][r] = p;
      s += p;
    }
  s += __shfl_xor(s, 16, 64);
  s += __shfl_xor(s, 32, 64);
  const float inv = 1.f / s;

  // ---- attn store (f32x4) + P' -> ps[q][k'] (r1-consumable layout) ----
  const int q = (w << 4) + l15;
  float* __restrict__ ab = attng + (size_t)b * (S_LEN * S_LEN);
  const float islen = inv * sqrtf((float)len);
#pragma unroll
  for (int nt = 0; nt < 4; ++nt) {
    int cs = (nt << 4) + (lq << 2);
    f32x4 pv = Ea[nt] * inv;
    if (q < S_LEN && cs < S_LEN) *(f32x4*)&ab[q * S_LEN + cs] = pv;
#pragma unroll
    for (int r = 0; r < 4; ++r) ps[swz<7>(q, cs + r)] = tobf(Ea[nt][r] * islen);
  }
  __syncthreads();  // B2: vt + ps visible

  // ---- GEMM3 (r1-proven): O = P' V ; O -> xs ----
  u16x8 ap[2];
#pragma unroll
  for (int kt = 0; kt < 2; ++kt)
    ap[kt] = *(const u16x8*)&ps[swz<7>((w << 4) + l15, (kt << 5) + (lq << 3))];
#pragma unroll
  for (int nt = 0; nt < 8; ++nt) {
    f32x4 a = f32x4{0.f, 0.f, 0.f, 0.f};
#pragma unroll
    for (int kt = 0; kt < 2; ++kt) {
      u16x8 bv = *(const u16x8*)&vt[swz<7>((nt << 4) + l15, (kt << 5) + (lq << 3))];
      a = MFMA(ap[kt], bv, a);
    }
    int dcol = (nt << 4) + l15;
    int rowb = (w << 4) + (lq << 2);
#pragma unroll
    for (int r = 0; r < 4; ++r) xs[swz<8>(rowb + r, dcol)] = f2bf(a[r]);
  }
  __syncthreads();  // B3: O visible

  // ---- GEMM4 (r1-proven): out = O @ Wo^T ----
  const unsigned short* __restrict__ wo = wbf + 3 * (DH * DH);
  u16x8 ao[4][4];
#pragma unroll
  for (int mt = 0; mt < 4; ++mt)
#pragma unroll
    for (int kt = 0; kt < 4; ++kt)
      ao[mt][kt] = *(const u16x8*)&xs[swz<8>((mt << 4) + l15, (kt << 5) + (lq << 3))];
  float* __restrict__ ob = outg + (size_t)b * (S_LEN * DH);
#pragma unroll
  for (int nt = 0; nt < 2; ++nt) {
    int dcol = n0w + (nt << 4) + l15;
    f32x4 acc[4];
#pragma unroll
    for (int mt = 0; mt < 4; ++mt) acc[mt] = f32x4{0.f, 0.f, 0.f, 0.f};
#pragma unroll
    for (int kt = 0; kt < 4; ++kt) {
      u16x8 bo = *(const u16x8*)&wo[dcol * DH + (kt << 5) + (lq << 3)];
#pragma unroll
      for (int mt = 0; mt < 4; ++mt) acc[mt] = MFMA(ao[mt][kt], bo, acc[mt]);
    }
#pragma unroll
    for (int mt = 0; mt < 4; ++mt) {
      int rowb = (mt << 4) + (lq << 2);
#pragma unroll
      for (int r = 0; r < 4; ++r) {
        int sr = rowb + r;
        if (sr < S_LEN) ob[sr * DH + dcol] = acc[mt][r];
      }
    }
  }
}

extern "C" void kernel_launch(void* const* d_in, const int* in_sizes, int n_in,
                              void* d_out, int out_size, void* d_ws, size_t ws_size,
                              hipStream_t stream) {
  const float* x  = (const float*)d_in[0];
  const float* wq = (const float*)d_in[1];
  const float* wk = (const float*)d_in[2];
  const float* wv = (const float*)d_in[3];
  const float* wo = (const float*)d_in[4];
  // d_in[5] = mask (redundant with len_sequence; unused)
  const int* lens = (const int*)d_in[6];
  const int B = in_sizes[6];  // 4096

  float* out = (float*)d_out;
  float* attn = out + (size_t)B * S_LEN * DH;
  unsigned short* wbf = (unsigned short*)d_ws;  // 4 x 128 x 128 bf16 = 128 KB

  conv_w<<<256, 256, 0, stream>>>(wq, wk, wv, wo, wbf);
  tb_fused<<<B, 256, 0, stream>>>(x, wbf, lens, out, attn);
}

// Round 6
// 112.412 us; speedup vs baseline: 1.8882x; 1.8847x over previous
//
#include <hip/hip_runtime.h>
#include <math.h>

#define S_LEN 56
#define DH 128

typedef float f32x4 __attribute__((ext_vector_type(4)));
typedef unsigned short u16x8 __attribute__((ext_vector_type(8)));
typedef unsigned short u16x4 __attribute__((ext_vector_type(4)));

__device__ __forceinline__ unsigned short f2bf(float f) {
  unsigned int u = __builtin_bit_cast(unsigned int, f);
  u += 0x7fffu + ((u >> 16) & 1u);  // RNE
  return (unsigned short)(u >> 16);
}
__device__ __forceinline__ unsigned short tobf(float f) {
  __bf16 h = (__bf16)f;
  return __builtin_bit_cast(unsigned short, h);
}
__device__ __forceinline__ u16x4 pk4(f32x4 v) {
  u16x4 r;
  r[0] = tobf(v[0]); r[1] = tobf(v[1]); r[2] = tobf(v[2]); r[3] = tobf(v[3]);
  return r;
}
__device__ __forceinline__ u16x8 pk8(f32x4 a, f32x4 b) {
  u16x8 r;
  r[0] = tobf(a[0]); r[1] = tobf(a[1]); r[2] = tobf(a[2]); r[3] = tobf(a[3]);
  r[4] = tobf(b[0]); r[5] = tobf(b[1]); r[6] = tobf(b[2]); r[7] = tobf(b[3]);
  return r;
}
__device__ __forceinline__ u16x8 cmb(u16x4 lo, u16x4 hi) {
  u16x8 r;
  r[0] = lo[0]; r[1] = lo[1]; r[2] = lo[2]; r[3] = lo[3];
  r[4] = hi[0]; r[5] = hi[1]; r[6] = hi[2]; r[7] = hi[3];
  return r;
}

template <typename V>
__device__ __forceinline__ auto mfma_sel(V a, V b, f32x4 c, int)
    -> decltype(__builtin_amdgcn_mfma_f32_16x16x32_bf16(a, b, c, 0, 0, 0)) {
  return __builtin_amdgcn_mfma_f32_16x16x32_bf16(a, b, c, 0, 0, 0);
}
template <typename V, typename E = __bf16>
__device__ __forceinline__ f32x4 mfma_sel(V a, V b, f32x4 c, long) {
  typedef E bfv __attribute__((ext_vector_type(8)));
  return __builtin_amdgcn_mfma_f32_16x16x32_bf16(
      __builtin_bit_cast(bfv, a), __builtin_bit_cast(bfv, b), c, 0, 0, 0);
}
__device__ __forceinline__ f32x4 MFMA(u16x8 a, u16x8 b, f32x4 c) {
  return mfma_sel(a, b, c, 0);
}

// XOR swizzle for row-major LDS tiles (row stride 2^LRB bytes).
template <int LRB>
__device__ __forceinline__ int swz(int row, int col) {
  int byteoff = (row << LRB) + (col << 1);
  byteoff ^= (row & 7) << 4;
  return byteoff >> 1;  // ushort index
}

__global__ void conv_w(const float* __restrict__ wq, const float* __restrict__ wk,
                       const float* __restrict__ wv, const float* __restrict__ wo,
                       unsigned short* __restrict__ o) {
  int i = blockIdx.x * 256 + threadIdx.x;  // 0..65535
  int m = i >> 14, r = i & 16383;
  const float* src = (m == 0) ? wq : (m == 1) ? wk : (m == 2) ? wv : wo;
  o[i] = f2bf(src[r]);
}

// One WAVE per sample; 4 independent waves per block; ZERO barriers.
// Register pipeline: x->af (regs) -> V (LDS vt, r1-proven layout) ->
// Q^T/K^T/E^T pair-packed (r5-proven) -> in-reg softmax -> pp (P^T, regs) ->
// O^T = V^T P^T (A: split-b64 pi-addressed vt reads) -> op (regs) ->
// out^T = Wo O^T (A: split-b64 pi-addressed global wo reads) -> f32x4 stores.
__global__ __launch_bounds__(256, 2) void tb_fused(
    const float* __restrict__ xg, const unsigned short* __restrict__ wbf,
    const int* __restrict__ lens, float* __restrict__ outg,
    float* __restrict__ attng) {
  __shared__ __align__(16) unsigned short vtl[4 * DH * 64];  // 64 KB: per-wave V^T

  const int tid = threadIdx.x;
  const int w = tid >> 6;        // wave id -> sample
  const int lane = tid & 63;
  const int l15 = lane & 15;
  const int lq = lane >> 4;      // 0..3
  const int b = blockIdx.x * 4 + w;
  unsigned short* vt = vtl + (w << 13);  // 128 rows x 64 cols u16

  const int len = lens[b];
  const float* __restrict__ xb = xg + (size_t)b * (S_LEN * DH);

  // ---- x -> registers af[mt][kt]: lane=row(l15), k=32kt+8lq+j ----
  u16x8 af[4][4];
#pragma unroll
  for (int mt = 0; mt < 4; ++mt) {
    int row = (mt << 4) + l15;
#pragma unroll
    for (int kt = 0; kt < 4; ++kt) {
      u16x8 h = {0, 0, 0, 0, 0, 0, 0, 0};
      if (row < S_LEN) {
        const float* p = xb + row * DH + (kt << 5) + (lq << 3);
        f32x4 v0 = *(const f32x4*)p;
        f32x4 v1 = *(const f32x4*)(p + 4);
        h = pk8(v0, v1);
      }
      af[mt][kt] = h;
    }
  }

  // ---- V = x @ Wv^T -> vt[d][s] (r1-proven store) ----
  {
    const unsigned short* __restrict__ wv = wbf + 2 * (DH * DH);
#pragma unroll
    for (int nt = 0; nt < 8; ++nt) {
      u16x8 bfr[4];
#pragma unroll
      for (int kt = 0; kt < 4; ++kt)
        bfr[kt] = *(const u16x8*)&wv[((nt << 4) + l15) * DH + (kt << 5) + (lq << 3)];
      f32x4 vacc[4];
#pragma unroll
      for (int mt = 0; mt < 4; ++mt) vacc[mt] = f32x4{0.f, 0.f, 0.f, 0.f};
#pragma unroll
      for (int kt = 0; kt < 4; ++kt)
#pragma unroll
        for (int mt = 0; mt < 4; ++mt)
          vacc[mt] = MFMA(af[mt][kt], bfr[kt], vacc[mt]);
      int d = (nt << 4) + l15;
#pragma unroll
      for (int mt = 0; mt < 4; ++mt)
        *(u16x4*)&vt[swz<7>(d, (mt << 4) + (lq << 2))] = pk4(vacc[mt]);
    }
  }

  // ---- E^T = K Q^T, pair-packed (r5-proven), all q-tiles ----
  f32x4 Ea[4][4];  // [qt][nt]; lane: q=16qt+l15, k'=16nt+4lq+r
#pragma unroll
  for (int qt = 0; qt < 4; ++qt)
#pragma unroll
    for (int nt = 0; nt < 4; ++nt) Ea[qt][nt] = f32x4{0.f, 0.f, 0.f, 0.f};

  const unsigned short* __restrict__ wqp = wbf;
  const unsigned short* __restrict__ wkp = wbf + DH * DH;
#pragma unroll
  for (int tp = 0; tp < 4; ++tp) {
    const int t0 = tp << 1, t1 = (tp << 1) | 1;
    u16x8 wf0[4], wf1[4];
#pragma unroll
    for (int kt = 0; kt < 4; ++kt) {
      wf0[kt] = *(const u16x8*)&wqp[((t0 << 4) + l15) * DH + (kt << 5) + (lq << 3)];
      wf1[kt] = *(const u16x8*)&wqp[((t1 << 4) + l15) * DH + (kt << 5) + (lq << 3)];
    }
    u16x8 qp[4];
#pragma unroll
    for (int qt = 0; qt < 4; ++qt) {
      f32x4 qa0 = {0.f, 0.f, 0.f, 0.f}, qa1 = {0.f, 0.f, 0.f, 0.f};
#pragma unroll
      for (int kt = 0; kt < 4; ++kt) {
        qa0 = MFMA(wf0[kt], af[qt][kt], qa0);
        qa1 = MFMA(wf1[kt], af[qt][kt], qa1);
      }
      qp[qt] = pk8(qa0, qa1);
    }
#pragma unroll
    for (int kt = 0; kt < 4; ++kt) {
      wf0[kt] = *(const u16x8*)&wkp[((t0 << 4) + l15) * DH + (kt << 5) + (lq << 3)];
      wf1[kt] = *(const u16x8*)&wkp[((t1 << 4) + l15) * DH + (kt << 5) + (lq << 3)];
    }
#pragma unroll
    for (int nt = 0; nt < 4; ++nt) {
      f32x4 ka0 = {0.f, 0.f, 0.f, 0.f}, ka1 = {0.f, 0.f, 0.f, 0.f};
#pragma unroll
      for (int kt = 0; kt < 4; ++kt) {
        ka0 = MFMA(wf0[kt], af[nt][kt], ka0);
        ka1 = MFMA(wf1[kt], af[nt][kt], ka1);
      }
      u16x8 kp = pk8(ka0, ka1);
#pragma unroll
      for (int qt = 0; qt < 4; ++qt)
        Ea[qt][nt] = MFMA(kp, qp[qt], Ea[qt][nt]);
    }
  }

  // ---- scale, mask, softmax per q-tile (per-lane row; shfl 16/32 reduce) ----
  const float sca = 0.08838834764831845f;  // 1/sqrt(128)
  float inv_[4];
#pragma unroll
  for (int qt = 0; qt < 4; ++qt) {
#pragma unroll
    for (int nt = 0; nt < 4; ++nt)
#pragma unroll
      for (int r = 0; r < 4; ++r) {
        int kk = (nt << 4) + (lq << 2) + r;
        Ea[qt][nt][r] = (kk < len) ? Ea[qt][nt][r] * sca : -1e30f;
      }
    float m = -1e30f;
#pragma unroll
    for (int nt = 0; nt < 4; ++nt)
      m = fmaxf(m, fmaxf(fmaxf(Ea[qt][nt][0], Ea[qt][nt][1]),
                         fmaxf(Ea[qt][nt][2], Ea[qt][nt][3])));
    m = fmaxf(m, __shfl_xor(m, 16, 64));
    m = fmaxf(m, __shfl_xor(m, 32, 64));
    float s = 0.f;
#pragma unroll
    for (int nt = 0; nt < 4; ++nt)
#pragma unroll
      for (int r = 0; r < 4; ++r) {
        float p = __expf(Ea[qt][nt][r] - m);
        Ea[qt][nt][r] = p;
        s += p;
      }
    s += __shfl_xor(s, 16, 64);
    s += __shfl_xor(s, 32, 64);
    inv_[qt] = 1.f / s;
  }

  // ---- attn store (f32x4) + P^T pack pp[c][qt] (pi-map, in regs) ----
  const float slen = sqrtf((float)len);
  float* __restrict__ ab = attng + (size_t)b * (S_LEN * S_LEN);
  u16x8 pp[2][4];
#pragma unroll
  for (int qt = 0; qt < 4; ++qt) {
    int q = (qt << 4) + l15;
    float iv = inv_[qt];
    float islen = iv * slen;
#pragma unroll
    for (int nt = 0; nt < 4; ++nt) {
      int cs = (nt << 4) + (lq << 2);
      f32x4 pv = Ea[qt][nt] * iv;
      if (q < S_LEN && cs < S_LEN) *(f32x4*)&ab[q * S_LEN + cs] = pv;
    }
    pp[0][qt] = pk8(Ea[qt][0] * islen, Ea[qt][1] * islen);
    pp[1][qt] = pk8(Ea[qt][2] * islen, Ea[qt][3] * islen);
  }

  // ---- O^T = V^T P^T : A from vt via split-b64 pi-addressing; op packed ----
  u16x8 op[4][4];  // [dp][qt]
#pragma unroll
  for (int dp = 0; dp < 4; ++dp) {
    f32x4 oa[2][4];
#pragma unroll
    for (int h = 0; h < 2; ++h) {
      int d = (((dp << 1) | h) << 4) + l15;
#pragma unroll
      for (int qt = 0; qt < 4; ++qt) oa[h][qt] = f32x4{0.f, 0.f, 0.f, 0.f};
#pragma unroll
      for (int c = 0; c < 2; ++c) {
        u16x4 lo = *(const u16x4*)&vt[swz<7>(d, (c << 5) + (lq << 2))];
        u16x4 hi = *(const u16x4*)&vt[swz<7>(d, (c << 5) + 16 + (lq << 2))];
        u16x8 a = cmb(lo, hi);
#pragma unroll
        for (int qt = 0; qt < 4; ++qt) oa[h][qt] = MFMA(a, pp[c][qt], oa[h][qt]);
      }
    }
#pragma unroll
    for (int qt = 0; qt < 4; ++qt) op[dp][qt] = pk8(oa[0][qt], oa[1][qt]);
  }

  // ---- out^T = Wo O^T : A from global wo via split-b64 pi-addressing ----
  const unsigned short* __restrict__ wop = wbf + 3 * (DH * DH);
  float* __restrict__ ob = outg + (size_t)b * (S_LEN * DH);
#pragma unroll
  for (int mo = 0; mo < 8; ++mo) {
    u16x8 wa[4];
#pragma unroll
    for (int c2 = 0; c2 < 4; ++c2) {
      const unsigned short* base = &wop[((mo << 4) + l15) * DH + (c2 << 5) + (lq << 2)];
      u16x4 lo = *(const u16x4*)base;
      u16x4 hi = *(const u16x4*)(base + 16);
      wa[c2] = cmb(lo, hi);
    }
#pragma unroll
    for (int qt = 0; qt < 4; ++qt) {
      f32x4 g = {0.f, 0.f, 0.f, 0.f};
#pragma unroll
      for (int c2 = 0; c2 < 4; ++c2) g = MFMA(wa[c2], op[c2][qt], g);
      int q = (qt << 4) + l15;
      if (q < S_LEN) *(f32x4*)&ob[q * DH + (mo << 4) + (lq << 2)] = g;
    }
  }
}

extern "C" void kernel_launch(void* const* d_in, const int* in_sizes, int n_in,
                              void* d_out, int out_size, void* d_ws, size_t ws_size,
                              hipStream_t stream) {
  const float* x  = (const float*)d_in[0];
  const float* wq = (const float*)d_in[1];
  const float* wk = (const float*)d_in[2];
  const float* wv = (const float*)d_in[3];
  const float* wo = (const float*)d_in[4];
  // d_in[5] = mask (redundant with len_sequence; unused)
  const int* lens = (const int*)d_in[6];
  const int B = in_sizes[6];  // 4096

  float* out = (float*)d_out;
  float* attn = out + (size_t)B * S_LEN * DH;
  unsigned short* wbf = (unsigned short*)d_ws;  // 4 x 128 x 128 bf16 = 128 KB

  conv_w<<<256, 256, 0, stream>>>(wq, wk, wv, wo, wbf);
  tb_fused<<<B / 4, 256, 0, stream>>>(x, wbf, lens, out, attn);
}